// Round 1
// baseline (184.767 us; speedup 1.0000x reference)
//
#include <hip/hip_runtime.h>

#define POOL 7
#define NCH 256
#define OUT_PER_BOX (NCH * POOL * POOL)   // 12544 = 7 * 1792
#define PARTS 7
#define PART_SZ (OUT_PER_BOX / PARTS)     // 1792 = 7 * 256
#define ITERS (PART_SZ / 256)             // 7
#define NXCD 8

// ---------------------------------------------------------------------------
// Kernel 1: sort boxes by (roi_level, morton(center)) so that spatially and
// level-adjacent boxes are adjacent in the schedule. Single block, bitonic.
// ---------------------------------------------------------------------------
__device__ __forceinline__ unsigned part1by1(unsigned x) {
    x &= 0x0000FFFFu;
    x = (x | (x << 8)) & 0x00FF00FFu;
    x = (x | (x << 4)) & 0x0F0F0F0Fu;
    x = (x | (x << 2)) & 0x33333333u;
    x = (x | (x << 1)) & 0x55555555u;
    return x;
}

__global__ __launch_bounds__(1024) void sort_boxes_kernel(
    const float* __restrict__ boxes, int* __restrict__ perm, int nbox)
{
    __shared__ unsigned s_key[1024];
    const int i = threadIdx.x;

    unsigned key = 0xFFFFFFFFu;   // pads sort to the end
    if (i < nbox) {
        const float y1 = boxes[i * 4 + 0];
        const float x1 = boxes[i * 4 + 1];
        const float y2 = boxes[i * 4 + 2];
        const float x2 = boxes[i * 4 + 3];
        const float h = y2 - y1;
        const float w = x2 - x1;
        const float lvlf = 4.0f + log2f(sqrtf(h * w) * (1.0f / 0.21875f));
        int lvl = (int)rintf(lvlf);
        lvl = lvl < 2 ? 2 : (lvl > 5 ? 5 : lvl);

        const float cy = 0.5f * (y1 + y2);
        const float cx = 0.5f * (x1 + x2);
        unsigned qy = (unsigned)fminf(511.0f, fmaxf(0.0f, cy * 512.0f));
        unsigned qx = (unsigned)fminf(511.0f, fmaxf(0.0f, cx * 512.0f));
        const unsigned morton = (part1by1(qy) << 1) | part1by1(qx);  // 18 bits

        // [31:28]=level-2, [27:10]=morton, [9:0]=box index (keys distinct)
        key = ((unsigned)(lvl - 2) << 28) | (morton << 10) | (unsigned)i;
    }
    s_key[i] = key;
    __syncthreads();

    for (int k = 2; k <= 1024; k <<= 1) {
        for (int j = k >> 1; j > 0; j >>= 1) {
            const int p = i ^ j;
            if (p > i) {
                const unsigned a = s_key[i];
                const unsigned b = s_key[p];
                const bool up = ((i & k) == 0);
                if ((a > b) == up) { s_key[i] = b; s_key[p] = a; }
            }
            __syncthreads();
        }
    }

    if (i < nbox) perm[i] = (int)(s_key[i] & 1023u);
}

// Fallback for nbox > 1024 (never hit with this harness): identity perm.
__global__ void identity_perm_kernel(int* __restrict__ perm, int nbox) {
    const int i = blockIdx.x * blockDim.x + threadIdx.x;
    if (i < nbox) perm[i] = i;
}

// ---------------------------------------------------------------------------
// Kernel 2: ROI-align. Body identical to the previous (verified) kernel;
// only the blockIdx -> box mapping changed:
//   xcd  = blockIdx % 8   (MI355X round-robins XCDs over blockIdx)
//   each XCD owns one contiguous cluster of cpx sorted boxes, so a cluster's
//   feature-map working set stays resident in that XCD's 4 MiB L2.
// ---------------------------------------------------------------------------
__global__ __launch_bounds__(256) void roi_align_kernel(
    const float* __restrict__ boxes,
    const float* __restrict__ p2,
    const float* __restrict__ p3,
    const float* __restrict__ p4,
    const float* __restrict__ p5,
    float* __restrict__ out,
    const int* __restrict__ perm,
    int nbox, int cpx)
{
    const int c    = blockIdx.x & (NXCD - 1);   // XCD id
    const int k    = blockIdx.x >> 3;           // slot within this XCD
    const int l    = k / PARTS;                 // local sorted-box index
    const int part = k - l * PARTS;
    const int s    = c * cpx + l;               // global sorted position
    if (s >= nbox) return;
    const int n = perm[s];                      // original box index
    const int tid = threadIdx.x;

    __shared__ int   s_y0[POOL], s_y1[POOL], s_xb[POOL], s_xcl[POOL];
    __shared__ float s_wy[POOL], s_wx[POOL], s_vy[POOL], s_vx[POOL];

    const float by1 = boxes[n * 4 + 0];
    const float bx1 = boxes[n * 4 + 1];
    const float by2 = boxes[n * 4 + 2];
    const float bx2 = boxes[n * 4 + 3];
    const float h = by2 - by1;
    const float w = bx2 - bx1;

    // roi_level = clip(round(4 + log2(sqrt(h*w) / (224/1024))), 2, 5)
    const float lvlf = 4.0f + log2f(sqrtf(h * w) / 0.21875f);
    int lvl = (int)rintf(lvlf);          // round-half-to-even, matches jnp.round
    lvl = lvl < 2 ? 2 : (lvl > 5 ? 5 : lvl);

    const float* fm;
    int H;
    switch (lvl) {
        case 2:  fm = p2; H = 256; break;
        case 3:  fm = p3; H = 128; break;
        case 4:  fm = p4; H = 64;  break;
        default: fm = p5; H = 32;  break;
    }
    const float Hm1 = (float)(H - 1);

    if (tid < POOL) {
        const float t = (float)tid * (1.0f / 6.0f);

        const float yy  = (by1 + h * t) * Hm1;
        const float y0f = floorf(yy);
        int y0 = (int)y0f;
        y0 = min(H - 1, max(0, y0));
        s_y0[tid] = y0;
        s_y1[tid] = min(H - 1, y0 + 1);
        s_wy[tid] = yy - y0f;                       // weight from UNCLIPPED floor
        s_vy[tid] = (yy >= 0.0f && yy <= Hm1) ? 1.0f : 0.0f;

        const float xx  = (bx1 + w * t) * Hm1;
        const float x0f = floorf(xx);
        int x0 = (int)x0f;
        x0 = min(H - 1, max(0, x0));
        // paired-load base: float2 at xb covers {xb, xb+1}.
        //   x0 <= H-2 : v00 = pair.x, v01 = pair.y   (x1 = x0+1)
        //   x0 == H-1 : v00 = v01 = pair.y           (x1 = x0, clamped)
        s_xb[tid]  = min(x0, H - 2);
        s_xcl[tid] = (x0 == H - 1) ? 1 : 0;
        s_wx[tid]  = xx - x0f;
        s_vx[tid]  = (xx >= 0.0f && xx <= Hm1) ? 1.0f : 0.0f;
    }
    __syncthreads();

    const size_t out_base = (size_t)n * OUT_PER_BOX + (size_t)part * PART_SZ;
    const int idx0 = part * PART_SZ + tid;
    const int HW = H * H;

    // Phase 1: issue all 14 dwordx2 gathers, keep results in registers.
    float2 q0[ITERS], q1[ITERS];
    #pragma unroll
    for (int i = 0; i < ITERS; ++i) {
        const int idx = idx0 + i * 256;
        const int cch = idx / 49;
        const int r   = idx - cch * 49;
        const int py  = r / 7;
        const int px  = r - py * 7;

        const float* fmc = fm + (size_t)cch * HW;
        const int xb = s_xb[px];
        q0[i] = *(const float2*)(fmc + s_y0[py] * H + xb);
        q1[i] = *(const float2*)(fmc + s_y1[py] * H + xb);
    }

    // Phase 2: lerp + store (coalesced).
    #pragma unroll
    for (int i = 0; i < ITERS; ++i) {
        const int idx = idx0 + i * 256;
        const int cch = idx / 49;
        const int r   = idx - cch * 49;
        const int py  = r / 7;
        const int px  = r - py * 7;

        const float wy = s_wy[py], wx = s_wx[px];
        const int   cl = s_xcl[px];

        const float v00 = cl ? q0[i].y : q0[i].x;
        const float v01 = q0[i].y;
        const float v10 = cl ? q1[i].y : q1[i].x;
        const float v11 = q1[i].y;

        const float r0 = v00 + wx * (v01 - v00);
        const float r1 = v10 + wx * (v11 - v10);
        float val = (r0 + wy * (r1 - r0)) * s_vy[py] * s_vx[px];

        out[out_base + (size_t)(i * 256 + tid)] = val;
    }
}

extern "C" void kernel_launch(void* const* d_in, const int* in_sizes, int n_in,
                              void* d_out, int out_size, void* d_ws, size_t ws_size,
                              hipStream_t stream) {
    const float* boxes = (const float*)d_in[0];
    const float* p2    = (const float*)d_in[1];
    const float* p3    = (const float*)d_in[2];
    const float* p4    = (const float*)d_in[3];
    const float* p5    = (const float*)d_in[4];
    float* out         = (float*)d_out;
    int*   perm        = (int*)d_ws;

    const int nbox = in_sizes[0] / 4;   // 1000
    const int cpx  = (nbox + NXCD - 1) / NXCD;   // boxes per XCD cluster (125)

    if (nbox <= 1024) {
        sort_boxes_kernel<<<1, 1024, 0, stream>>>(boxes, perm, nbox);
    } else {
        identity_perm_kernel<<<(nbox + 255) / 256, 256, 0, stream>>>(perm, nbox);
    }

    roi_align_kernel<<<NXCD * cpx * PARTS, 256, 0, stream>>>(
        boxes, p2, p3, p4, p5, out, perm, nbox, cpx);
}

// Round 2
// 155.142 us; speedup vs baseline: 1.1910x; 1.1910x over previous
//
#include <hip/hip_runtime.h>

#define POOL 7
#define NCH 256
#define OUT_PER_BOX (NCH * POOL * POOL)   // 12544 = 7 * 1792
#define PARTS 7
#define PART_SZ (OUT_PER_BOX / PARTS)     // 1792 = 7 * 256
#define ITERS (PART_SZ / 256)             // 7
#define NXCD 8
#define CHB 8                              // boxes per deal-chunk
#define CHU (CHB * PARTS)                  // 56 work-units per chunk (box-aligned)
#define GRPU (NXCD * CHU)                  // 448 work-units per deal round

// ---------------------------------------------------------------------------
// Kernel 1: counting sort of boxes into 64 bins = (level, 4x4 spatial quadrant).
// Order within a bin is arbitrary (atomic scatter) — output is indexed by the
// ORIGINAL box id, so perm order only affects the schedule, not correctness.
// 3 barriers, single block: ~3 us.
// ---------------------------------------------------------------------------
#define NBINS 64

__global__ __launch_bounds__(1024) void bin_boxes_kernel(
    const float* __restrict__ boxes, int* __restrict__ perm, int nbox)
{
    __shared__ int s_cnt[NBINS];
    __shared__ int s_off[NBINS];
    const int i = threadIdx.x;

    if (i < NBINS) s_cnt[i] = 0;
    __syncthreads();

    int bin = -1;
    if (i < nbox) {
        const float y1 = boxes[i * 4 + 0];
        const float x1 = boxes[i * 4 + 1];
        const float y2 = boxes[i * 4 + 2];
        const float x2 = boxes[i * 4 + 3];
        const float h = y2 - y1;
        const float w = x2 - x1;
        const float lvlf = 4.0f + log2f(sqrtf(h * w) * (1.0f / 0.21875f));
        int lvl = (int)rintf(lvlf);
        lvl = lvl < 2 ? 2 : (lvl > 5 ? 5 : lvl);

        const float cy = 0.5f * (y1 + y2);
        const float cx = 0.5f * (x1 + x2);
        int qy = (int)(cy * 4.0f); qy = qy < 0 ? 0 : (qy > 3 ? 3 : qy);
        int qx = (int)(cx * 4.0f); qx = qx < 0 ? 0 : (qx > 3 ? 3 : qx);

        bin = ((lvl - 2) << 4) | (qy << 2) | qx;
        atomicAdd(&s_cnt[bin], 1);
    }
    __syncthreads();

    if (i == 0) {
        int acc = 0;
        for (int b = 0; b < NBINS; ++b) { s_off[b] = acc; acc += s_cnt[b]; }
    }
    __syncthreads();

    if (i < nbox) {
        const int pos = atomicAdd(&s_off[bin], 1);
        perm[pos] = i;
    }
}

// Fallback for nbox > 1024 (never hit with this harness): identity perm.
__global__ void identity_perm_kernel(int* __restrict__ perm, int nbox) {
    const int i = blockIdx.x * blockDim.x + threadIdx.x;
    if (i < nbox) perm[i] = i;
}

// ---------------------------------------------------------------------------
// Kernel 2: ROI-align. Body identical to the verified round-0 kernel; only the
// blockIdx -> (box, part) mapping changed:
//   hardware: xcd = blockIdx % 8 (round-robin)
//   schedule: sorted boxes are dealt to XCDs in 8-box chunks, round-robin.
//   -> per-XCD level mix is balanced (fixes round-1's tail imbalance) while
//      same-bin boxes stay co-resident on one XCD (keeps FETCH_SIZE halved).
// ---------------------------------------------------------------------------
__global__ __launch_bounds__(256) void roi_align_kernel(
    const float* __restrict__ boxes,
    const float* __restrict__ p2,
    const float* __restrict__ p3,
    const float* __restrict__ p4,
    const float* __restrict__ p5,
    float* __restrict__ out,
    const int* __restrict__ perm,
    int nbox, int total_u)
{
    const int xcd    = blockIdx.x & (NXCD - 1);
    const int t      = blockIdx.x >> 3;
    const int grp    = t / CHU;
    const int within = t - grp * CHU;
    const int u      = grp * GRPU + xcd * CHU + within;   // bijective over padded grid
    if (u >= total_u) return;
    const int s    = u / PARTS;
    const int part = u - s * PARTS;
    const int n    = perm[s];
    const int tid  = threadIdx.x;

    __shared__ int   s_y0[POOL], s_y1[POOL], s_xb[POOL], s_xcl[POOL];
    __shared__ float s_wy[POOL], s_wx[POOL], s_vy[POOL], s_vx[POOL];

    const float by1 = boxes[n * 4 + 0];
    const float bx1 = boxes[n * 4 + 1];
    const float by2 = boxes[n * 4 + 2];
    const float bx2 = boxes[n * 4 + 3];
    const float h = by2 - by1;
    const float w = bx2 - bx1;

    // roi_level = clip(round(4 + log2(sqrt(h*w) / (224/1024))), 2, 5)
    const float lvlf = 4.0f + log2f(sqrtf(h * w) / 0.21875f);
    int lvl = (int)rintf(lvlf);          // round-half-to-even, matches jnp.round
    lvl = lvl < 2 ? 2 : (lvl > 5 ? 5 : lvl);

    const float* fm;
    int H;
    switch (lvl) {
        case 2:  fm = p2; H = 256; break;
        case 3:  fm = p3; H = 128; break;
        case 4:  fm = p4; H = 64;  break;
        default: fm = p5; H = 32;  break;
    }
    const float Hm1 = (float)(H - 1);

    if (tid < POOL) {
        const float t7 = (float)tid * (1.0f / 6.0f);

        const float yy  = (by1 + h * t7) * Hm1;
        const float y0f = floorf(yy);
        int y0 = (int)y0f;
        y0 = min(H - 1, max(0, y0));
        s_y0[tid] = y0;
        s_y1[tid] = min(H - 1, y0 + 1);
        s_wy[tid] = yy - y0f;                       // weight from UNCLIPPED floor
        s_vy[tid] = (yy >= 0.0f && yy <= Hm1) ? 1.0f : 0.0f;

        const float xx  = (bx1 + w * t7) * Hm1;
        const float x0f = floorf(xx);
        int x0 = (int)x0f;
        x0 = min(H - 1, max(0, x0));
        // paired-load base: float2 at xb covers {xb, xb+1}.
        //   x0 <= H-2 : v00 = pair.x, v01 = pair.y   (x1 = x0+1)
        //   x0 == H-1 : v00 = v01 = pair.y           (x1 = x0, clamped)
        s_xb[tid]  = min(x0, H - 2);
        s_xcl[tid] = (x0 == H - 1) ? 1 : 0;
        s_wx[tid]  = xx - x0f;
        s_vx[tid]  = (xx >= 0.0f && xx <= Hm1) ? 1.0f : 0.0f;
    }
    __syncthreads();

    const size_t out_base = (size_t)n * OUT_PER_BOX + (size_t)part * PART_SZ;
    const int idx0 = part * PART_SZ + tid;
    const int HW = H * H;

    // Phase 1: issue all 14 dwordx2 gathers, keep results in registers.
    float2 q0[ITERS], q1[ITERS];
    #pragma unroll
    for (int i = 0; i < ITERS; ++i) {
        const int idx = idx0 + i * 256;
        const int cch = idx / 49;
        const int r   = idx - cch * 49;
        const int py  = r / 7;
        const int px  = r - py * 7;

        const float* fmc = fm + (size_t)cch * HW;
        const int xb = s_xb[px];
        q0[i] = *(const float2*)(fmc + s_y0[py] * H + xb);
        q1[i] = *(const float2*)(fmc + s_y1[py] * H + xb);
    }

    // Phase 2: lerp + store (coalesced).
    #pragma unroll
    for (int i = 0; i < ITERS; ++i) {
        const int idx = idx0 + i * 256;
        const int cch = idx / 49;
        const int r   = idx - cch * 49;
        const int py  = r / 7;
        const int px  = r - py * 7;

        const float wy = s_wy[py], wx = s_wx[px];
        const int   cl = s_xcl[px];

        const float v00 = cl ? q0[i].y : q0[i].x;
        const float v01 = q0[i].y;
        const float v10 = cl ? q1[i].y : q1[i].x;
        const float v11 = q1[i].y;

        const float r0 = v00 + wx * (v01 - v00);
        const float r1 = v10 + wx * (v11 - v10);
        float val = (r0 + wy * (r1 - r0)) * s_vy[py] * s_vx[px];

        out[out_base + (size_t)(i * 256 + tid)] = val;
    }
}

extern "C" void kernel_launch(void* const* d_in, const int* in_sizes, int n_in,
                              void* d_out, int out_size, void* d_ws, size_t ws_size,
                              hipStream_t stream) {
    const float* boxes = (const float*)d_in[0];
    const float* p2    = (const float*)d_in[1];
    const float* p3    = (const float*)d_in[2];
    const float* p4    = (const float*)d_in[3];
    const float* p5    = (const float*)d_in[4];
    float* out         = (float*)d_out;
    int*   perm        = (int*)d_ws;

    const int nbox    = in_sizes[0] / 4;        // 1000
    const int total_u = nbox * PARTS;           // 7000
    const int grid    = ((total_u + GRPU - 1) / GRPU) * GRPU;   // pad to 448 -> 7168

    if (nbox <= 1024) {
        bin_boxes_kernel<<<1, 1024, 0, stream>>>(boxes, perm, nbox);
    } else {
        identity_perm_kernel<<<(nbox + 255) / 256, 256, 0, stream>>>(perm, nbox);
    }

    roi_align_kernel<<<grid, 256, 0, stream>>>(
        boxes, p2, p3, p4, p5, out, perm, nbox, total_u);
}